// Round 1
// baseline (531.075 us; speedup 1.0000x reference)
//
#include <hip/hip_runtime.h>

// Problem constants (from reference)
constexpr int LAYER_IDX = 5;
constexpr int WINDOW    = 13;
constexpr int B         = 8;
constexpr int L         = 6656;          // divisible by WINDOW
constexpr int D         = 1024;
constexpr int CH        = L / WINDOW;    // 512 groups per window row
constexpr int D2        = D / 2;         // float2 columns = 512

// Use clang ext_vector for clean codegen (.x/.y swizzles, plain 8B loads)
typedef float vf2 __attribute__((ext_vector_type(2)));

// Compare-exchange on 2 independent lanes (float2 components)
__device__ __forceinline__ void ce(vf2& a, vf2& b) {
    vf2 lo, hi;
    lo.x = fminf(a.x, b.x); hi.x = fmaxf(a.x, b.x);
    lo.y = fminf(a.y, b.y); hi.y = fmaxf(a.y, b.y);
    a = lo; b = hi;
}

// One thread handles one (b, c, d2): gathers 13 float2 rows at stride CH*D2,
// sorts the 13 values per component, scatters back to the same offsets.
// float2 (not float4) per thread: val[13] = 26 VGPRs instead of 52, and the
// index array is recomputed at store time instead of kept live.  Target is
// <=64 VGPRs -> 8 waves/SIMD (vs ~4 before), enforced by __launch_bounds__.
// Each wave still loads/stores 512B contiguous segments (8B/lane) per access.
__global__ __launch_bounds__(256, 8)
void SWD16_sortwin_kernel(const vf2* __restrict__ v, vf2* __restrict__ out) {
    const int tid = blockIdx.x * blockDim.x + threadIdx.x;
    const int d2  = tid & (D2 - 1);          // D2 = 512
    const int bc  = tid >> 9;                // (b*CH + c)
    const int c   = bc & (CH - 1);           // CH = 512
    const int b   = bc >> 9;

    const vf2* __restrict__ vb = v   + (size_t)b * (L * D2);
    vf2*       __restrict__ ob = out + (size_t)b * (L * D2);

    vf2 val[WINDOW];

    #pragma unroll
    for (int w = 0; w < WINDOW; ++w) {
        int p = w * CH + c + LAYER_IDX;      // max 12*512+511+5 = 6660
        if (p >= L) p -= L;                  // wrap (only w=12, c>=507)
        val[w] = vb[p * D2 + d2];
    }

    // Odd-even transposition sort: 13 rounds, correct for n=13, branch-free.
    // VALU cost is ~8us aggregate across the whole grid -- not the bottleneck.
    #pragma unroll
    for (int r = 0; r < WINDOW; ++r) {
        #pragma unroll
        for (int i = (r & 1); i + 1 < WINDOW; i += 2) {
            ce(val[i], val[i + 1]);
        }
    }

    #pragma unroll
    for (int w = 0; w < WINDOW; ++w) {
        int p = w * CH + c + LAYER_IDX;      // recompute: 3 VALU ops, saves 13 VGPRs
        if (p >= L) p -= L;
        ob[p * D2 + d2] = val[w];
    }
}

extern "C" void kernel_launch(void* const* d_in, const int* in_sizes, int n_in,
                              void* d_out, int out_size, void* d_ws, size_t ws_size,
                              hipStream_t stream) {
    // inputs: d_in[0]=q (unused), d_in[1]=k (unused), d_in[2]=v (float32)
    const vf2* v   = (const vf2*)d_in[2];
    vf2*       out = (vf2*)d_out;

    const int total_threads = B * CH * D2;   // 2,097,152
    const int block = 256;
    const int grid  = total_threads / block; // 8192
    SWD16_sortwin_kernel<<<grid, block, 0, stream>>>(v, out);
}

// Round 2
// 522.426 us; speedup vs baseline: 1.0166x; 1.0166x over previous
//
#include <hip/hip_runtime.h>

// Problem constants (from reference)
constexpr int LAYER_IDX = 5;
constexpr int WINDOW    = 13;
constexpr int B         = 8;
constexpr int L         = 6656;          // divisible by WINDOW
constexpr int D         = 1024;
constexpr int CH        = L / WINDOW;    // 512 groups per window row
constexpr int D4        = D / 4;         // float4 columns = 256
constexpr int K         = 4;             // c-tiles per block (pipeline depth)
constexpr int BPB       = CH / K;        // blocks per batch b = 128

// Compare-exchange on 4 independent lanes (float4 components)
__device__ __forceinline__ void ce(float4& a, float4& b) {
    float4 lo, hi;
    lo.x = fminf(a.x, b.x); hi.x = fmaxf(a.x, b.x);
    lo.y = fminf(a.y, b.y); hi.y = fmaxf(a.y, b.y);
    lo.z = fminf(a.z, b.z); hi.z = fmaxf(a.z, b.z);
    lo.w = fminf(a.w, b.w); hi.w = fmaxf(a.w, b.w);
    a = lo; b = hi;
}

// Software-pipelined version: each block owns K=4 consecutive c values of one
// batch b; 256 threads = all 256 float4 columns.  Register double buffer:
// while tile i is sorted (pure VALU, ~600 cy), tile i+1's 13 loads are already
// in flight -- the compiler's vmcnt accounting waits only on the current
// buffer's loads.  This removes the chip-wide "memory dark" gaps of the
// phase-locked single-tile version (loads -> drain -> sort -> store -> exit).
// Grid = 1024 blocks = 4 blocks/CU, co-resident at 4 waves/SIMD (<=128 VGPR,
// enforced below): zero wave-generation turnover.
__global__ __launch_bounds__(256, 4)
void SWD16_sortwin_kernel(const float4* __restrict__ v, float4* __restrict__ out) {
    const int d4 = threadIdx.x;                 // 0..255
    const int bk = blockIdx.x;                  // 0..B*BPB-1
    const int c0 = (bk & (BPB - 1)) * K;        // base c for this block
    const int b  = bk >> 7;                     // BPB = 128

    const float4* __restrict__ vb = v   + (size_t)b * (L * D4);
    float4*       __restrict__ ob = out + (size_t)b * (L * D4);

    float4 val[2][WINDOW];                      // 104 VGPRs, statically indexed

    // Prologue: issue loads for tile 0.
    #pragma unroll
    for (int w = 0; w < WINDOW; ++w) {
        int p = w * CH + c0 + LAYER_IDX;
        if (p >= L) p -= L;                     // wrap (only w=12, c>=507)
        val[0][w] = vb[p * D4 + d4];
    }

    #pragma unroll
    for (int i = 0; i < K; ++i) {
        const int cur = i & 1;                  // compile-time after unroll
        const int nxt = cur ^ 1;

        // Issue next tile's loads BEFORE sorting the current one: they stay
        // in flight under the ~600-cycle VALU sort.
        if (i + 1 < K) {
            #pragma unroll
            for (int w = 0; w < WINDOW; ++w) {
                int p = w * CH + (c0 + i + 1) + LAYER_IDX;
                if (p >= L) p -= L;
                val[nxt][w] = vb[p * D4 + d4];
            }
        }

        // Odd-even transposition sort: 13 rounds, correct for n=13, branch-free.
        #pragma unroll
        for (int r = 0; r < WINDOW; ++r) {
            #pragma unroll
            for (int j = (r & 1); j + 1 < WINDOW; j += 2) {
                ce(val[cur][j], val[cur][j + 1]);
            }
        }

        // Store current tile (recompute offsets: 3 VALU ops each, keeps no
        // index array live across the pipeline).
        #pragma unroll
        for (int w = 0; w < WINDOW; ++w) {
            int p = w * CH + (c0 + i) + LAYER_IDX;
            if (p >= L) p -= L;
            ob[p * D4 + d4] = val[cur][w];
        }
    }
}

extern "C" void kernel_launch(void* const* d_in, const int* in_sizes, int n_in,
                              void* d_out, int out_size, void* d_ws, size_t ws_size,
                              hipStream_t stream) {
    // inputs: d_in[0]=q (unused), d_in[1]=k (unused), d_in[2]=v (float32)
    const float4* v   = (const float4*)d_in[2];
    float4*       out = (float4*)d_out;

    const int grid  = B * BPB;               // 1024 blocks
    const int block = 256;                   // = D4 threads
    SWD16_sortwin_kernel<<<grid, block, 0, stream>>>(v, out);
}